// Round 1
// baseline (402.043 us; speedup 1.0000x reference)
//
#include <hip/hip_runtime.h>
#include <hip/hip_bf16.h>

// Problem constants (L=1024, B=4, E=1024, H=16, D=64)
#define SL 1024
#define BB 4
#define EE 1024
#define HH 16
#define DD 64
#define BHC 64          // BB*HH
#define M1 4096         // SL*BB

typedef __bf16 bf16x8 __attribute__((ext_vector_type(8)));
typedef __bf16 bf16x4 __attribute__((ext_vector_type(4)));
typedef float f32x4 __attribute__((ext_vector_type(4)));

__device__ __forceinline__ f32x4 mfma16(bf16x8 a, bf16x8 b, f32x4 c) {
    return __builtin_amdgcn_mfma_f32_16x16x32_bf16(a, b, c, 0, 0, 0);
}

// ---------------- conversion kernels ----------------
__global__ __launch_bounds__(256) void f32_to_bf16_k(const float* __restrict__ in,
                                                     __bf16* __restrict__ out, int n) {
    int idx = (blockIdx.x * 256 + threadIdx.x) * 4;
    if (idx >= n) return;
    float4 v = *(const float4*)&in[idx];
    bf16x4 o;
    o[0] = (__bf16)v.x; o[1] = (__bf16)v.y; o[2] = (__bf16)v.z; o[3] = (__bf16)v.w;
    *(bf16x4*)&out[idx] = o;
}

// erf[r][d] = relpos[1023-r][d], bf16
__global__ __launch_bounds__(256) void erflip_k(const float* __restrict__ rel,
                                                __bf16* __restrict__ erf) {
    int idx = blockIdx.x * 256 + threadIdx.x;   // 65536 total
    int r = idx >> 6, d = idx & 63;
    erf[idx] = (__bf16)rel[(1023 - r) * 64 + d];
}

// ---------------- GEMM: C = A(MxK) @ B(NxK)^T + bias ----------------
// mode 0: scatter to q/k/v bh-major bf16 (q scaled by 0.125)
// mode 1: plain fp32 store to outf (M x N)
#define BMt 128
#define BNt 128
#define BKt 32
#define LDK 40
__global__ __launch_bounds__(256) void gemm_bt(const __bf16* __restrict__ A,
                                               const __bf16* __restrict__ Bm,
                                               const float* __restrict__ bias,
                                               int M, int N, int K, int mode,
                                               __bf16* __restrict__ q_ws,
                                               __bf16* __restrict__ k_ws,
                                               __bf16* __restrict__ v_ws,
                                               float* __restrict__ outf) {
    __shared__ __bf16 As[BMt * LDK];
    __shared__ __bf16 Bs[BNt * LDK];
    int tid = threadIdx.x;
    int wave = tid >> 6, lane = tid & 63;
    int quad = lane >> 4, c = lane & 15;
    int ntiles = N / BNt;
    int bx = blockIdx.x % ntiles, by = blockIdx.x / ntiles;
    int m0 = by * BMt, n0 = bx * BNt;
    int wm = (wave >> 1) * 64, wn = (wave & 1) * 64;

    f32x4 acc[4][4] = {};
    for (int k0 = 0; k0 < K; k0 += BKt) {
        __syncthreads();
#pragma unroll
        for (int ch = 0; ch < 2; ++ch) {
            int p = tid + ch * 256;
            int row = p >> 2, col = (p & 3) * 8;
            *(bf16x8*)&As[row * LDK + col] = *(const bf16x8*)&A[(long)(m0 + row) * K + k0 + col];
            *(bf16x8*)&Bs[row * LDK + col] = *(const bf16x8*)&Bm[(long)(n0 + row) * K + k0 + col];
        }
        __syncthreads();
        bf16x8 af[4], bfr[4];
#pragma unroll
        for (int t = 0; t < 4; ++t) {
            af[t]  = *(const bf16x8*)&As[(wm + t * 16 + c) * LDK + quad * 8];
            bfr[t] = *(const bf16x8*)&Bs[(wn + t * 16 + c) * LDK + quad * 8];
        }
#pragma unroll
        for (int mt = 0; mt < 4; ++mt)
#pragma unroll
            for (int nt = 0; nt < 4; ++nt)
                acc[mt][nt] = mfma16(af[mt], bfr[nt], acc[mt][nt]);
    }
    // epilogue
#pragma unroll
    for (int mt = 0; mt < 4; ++mt) {
#pragma unroll
        for (int nt = 0; nt < 4; ++nt) {
            int nn = n0 + wn + nt * 16 + c;
            float bv = bias[nn];
#pragma unroll
            for (int i = 0; i < 4; ++i) {
                int mm = m0 + wm + mt * 16 + quad * 4 + i;
                float v = acc[mt][nt][i] + bv;
                if (mode == 0) {
                    int which = nn >> 10;
                    int cc = nn & 1023;
                    int h = cc >> 6, d = cc & 63;
                    int l = mm >> 2, b = mm & 3;
                    long off = ((long)(b * 16 + h) * 1024 + l) * 64 + d;
                    if (which == 0)      q_ws[off] = (__bf16)(v * 0.125f);
                    else if (which == 1) k_ws[off] = (__bf16)v;
                    else                 v_ws[off] = (__bf16)v;
                } else {
                    outf[(long)mm * N + nn] = v;
                }
            }
        }
    }
}

// ---------------- V transpose: [bh][m][d] -> [bh][d][m] ----------------
__global__ __launch_bounds__(256) void transpose_v(const __bf16* __restrict__ v_ws,
                                                   __bf16* __restrict__ vT_ws) {
    __shared__ __bf16 t[64 * 72];
    int bh = blockIdx.x >> 4, mt = blockIdx.x & 15;
    int tid = threadIdx.x;
    int r = tid >> 2, cg = (tid & 3) * 16;
    const __bf16* src = v_ws + ((long)bh * 1024 + mt * 64) * 64;
    *(bf16x8*)&t[r * 72 + cg]     = *(const bf16x8*)&src[r * 64 + cg];
    *(bf16x8*)&t[r * 72 + cg + 8] = *(const bf16x8*)&src[r * 64 + cg + 8];
    __syncthreads();
    __bf16 tmp[16] __attribute__((aligned(16)));
#pragma unroll
    for (int j = 0; j < 16; ++j) tmp[j] = t[(cg + j) * 72 + r];
    __bf16* dst = vT_ws + ((long)bh * 64 + r) * 1024 + mt * 64 + cg;
    *(bf16x8*)&dst[0] = *(const bf16x8*)&tmp[0];
    *(bf16x8*)&dst[8] = *(const bf16x8*)&tmp[8];
}

// ---------------- attention ----------------
// grid: 64 bh * 64 l-tiles; block 256 (4 waves). Wave w owns key cols [256w,256w+256).
#define LDP 1032
__global__ __launch_bounds__(256) void attn_kernel(const __bf16* __restrict__ q_ws,
                                                   const __bf16* __restrict__ k_ws,
                                                   const __bf16* __restrict__ vT_ws,
                                                   const __bf16* __restrict__ erf,
                                                   __bf16* __restrict__ O_flat) {
    __shared__ __bf16 RP[16 * LDP];      // R (rel) then reused for P
    __shared__ float smax[4][16];
    __shared__ float ssum[4][16];

    int tid = threadIdx.x;
    int w = tid >> 6, lane = tid & 63;
    int quad = lane >> 4, c = lane & 15;
    int bh = blockIdx.x >> 6;
    int l0 = (blockIdx.x & 63) * 16;
    int b = bh >> 4, h = bh & 15;

    const __bf16* qp = q_ws + ((long)bh * 1024 + l0) * 64;
    bf16x8 aq0 = *(const bf16x8*)&qp[c * 64 + quad * 8];
    bf16x8 aq1 = *(const bf16x8*)&qp[c * 64 + 32 + quad * 8];

    // Phase R: R[l][r] = q[l] . erf[r], r in [0, l0+15]
    for (int t = 0; t < 16; ++t) {
        int r0 = w * 256 + t * 16;
        if (r0 > l0 + 15) break;
        const __bf16* ep = erf + (long)r0 * 64;
        bf16x8 b0 = *(const bf16x8*)&ep[c * 64 + quad * 8];
        bf16x8 b1 = *(const bf16x8*)&ep[c * 64 + 32 + quad * 8];
        f32x4 ar = {0.f, 0.f, 0.f, 0.f};
        ar = mfma16(aq0, b0, ar);
        ar = mfma16(aq1, b1, ar);
#pragma unroll
        for (int i = 0; i < 4; ++i)
            RP[(quad * 4 + i) * LDP + r0 + c] = (__bf16)ar[i];
    }
    __syncthreads();

    // Phase S: scores = Q K^T + rel
    f32x4 S[16];
    const __bf16* kp = k_ws + (long)bh * 1024 * 64;
#pragma unroll 4
    for (int t = 0; t < 16; ++t) {
        int m0 = w * 256 + t * 16;
        bf16x8 b0 = *(const bf16x8*)&kp[(m0 + c) * 64 + quad * 8];
        bf16x8 b1 = *(const bf16x8*)&kp[(m0 + c) * 64 + 32 + quad * 8];
        f32x4 acc = {0.f, 0.f, 0.f, 0.f};
        acc = mfma16(aq0, b0, acc);
        acc = mfma16(aq1, b1, acc);
#pragma unroll
        for (int i = 0; i < 4; ++i) {
            int l = l0 + quad * 4 + i;
            int r = l - (m0 + c);
            if (r >= 0) acc[i] += (float)RP[(quad * 4 + i) * LDP + r];
        }
        S[t] = acc;
    }

    // row max (rows quad*4+i live in the 16 lanes of this quad)
    float gmax[4];
    {
        float mx[4];
#pragma unroll
        for (int i = 0; i < 4; ++i) {
            float m = S[0][i];
#pragma unroll
            for (int t = 1; t < 16; ++t) m = fmaxf(m, S[t][i]);
            for (int s = 1; s < 16; s <<= 1) m = fmaxf(m, __shfl_xor(m, s));
            mx[i] = m;
        }
        if (c == 0)
#pragma unroll
            for (int i = 0; i < 4; ++i) smax[w][quad * 4 + i] = mx[i];
    }
    __syncthreads();
#pragma unroll
    for (int i = 0; i < 4; ++i)
        gmax[i] = fmaxf(fmaxf(smax[0][quad * 4 + i], smax[1][quad * 4 + i]),
                        fmaxf(smax[2][quad * 4 + i], smax[3][quad * 4 + i]));

    // P = exp(S - gmax); write to LDS (reuse R buffer; all R reads done at barrier above)
    float sum[4] = {0.f, 0.f, 0.f, 0.f};
#pragma unroll 4
    for (int t = 0; t < 16; ++t) {
        int m0 = w * 256 + t * 16;
        f32x4 p;
#pragma unroll
        for (int i = 0; i < 4; ++i) {
            p[i] = __expf(S[t][i] - gmax[i]);
            sum[i] += p[i];
        }
#pragma unroll
        for (int i = 0; i < 4; ++i)
            RP[(quad * 4 + i) * LDP + m0 + c] = (__bf16)p[i];
    }
#pragma unroll
    for (int i = 0; i < 4; ++i)
        for (int s = 1; s < 16; s <<= 1) sum[i] += __shfl_xor(sum[i], s);
    if (c == 0)
#pragma unroll
        for (int i = 0; i < 4; ++i) ssum[w][quad * 4 + i] = sum[i];
    __syncthreads();
    float rs[4];
#pragma unroll
    for (int i = 0; i < 4; ++i) {
        float g = ssum[0][quad * 4 + i] + ssum[1][quad * 4 + i] +
                  ssum[2][quad * 4 + i] + ssum[3][quad * 4 + i];
        rs[i] = 1.0f / g;
    }

    // Phase PV: wave w computes d-tile w (16 d cols), contracting over all 1024 m
    f32x4 o = {0.f, 0.f, 0.f, 0.f};
    const __bf16* vp = vT_ws + (long)bh * 64 * 1024 + (long)(w * 16 + c) * 1024;
#pragma unroll 8
    for (int ks = 0; ks < 32; ++ks) {
        bf16x8 pa = *(const bf16x8*)&RP[c * LDP + ks * 32 + quad * 8];
        bf16x8 vb = *(const bf16x8*)&vp[ks * 32 + quad * 8];
        o = mfma16(pa, vb, o);
    }
#pragma unroll
    for (int i = 0; i < 4; ++i) {
        int l = l0 + quad * 4 + i;
        long row = (long)l * 4 + b;
        int col = h * 64 + w * 16 + c;
        O_flat[row * 1024 + col] = (__bf16)(o[i] * rs[i]);
    }
}

// ---------------- launch ----------------
extern "C" void kernel_launch(void* const* d_in, const int* in_sizes, int n_in,
                              void* d_out, int out_size, void* d_ws, size_t ws_size,
                              hipStream_t stream) {
    const float* query  = (const float*)d_in[0];
    const float* relpos = (const float*)d_in[1];
    const float* w_in   = (const float*)d_in[2];
    const float* b_in   = (const float*)d_in[3];
    const float* w_out  = (const float*)d_in[4];
    const float* b_out  = (const float*)d_in[5];
    float* out = (float*)d_out;

    char* ws = (char*)d_ws;
    size_t off = 0;
    auto alloc = [&](size_t bytes) {
        void* p = ws + off;
        off += (bytes + 255) & ~(size_t)255;
        return p;
    };
    __bf16* qA    = (__bf16*)alloc((size_t)M1 * EE * 2);        // query bf16
    __bf16* winb  = (__bf16*)alloc((size_t)3 * EE * EE * 2);    // in_proj_weight bf16
    __bf16* woutb = (__bf16*)alloc((size_t)EE * EE * 2);        // out_proj_weight bf16
    __bf16* erfp  = (__bf16*)alloc((size_t)SL * DD * 2);        // flipped er bf16
    __bf16* q_ws  = (__bf16*)alloc((size_t)BHC * SL * DD * 2);
    __bf16* k_ws  = (__bf16*)alloc((size_t)BHC * SL * DD * 2);
    __bf16* v_ws  = (__bf16*)alloc((size_t)BHC * SL * DD * 2);
    __bf16* vT_ws = (__bf16*)alloc((size_t)BHC * SL * DD * 2);
    __bf16* O_flat= (__bf16*)alloc((size_t)M1 * EE * 2);

    f32_to_bf16_k<<<4096, 256, 0, stream>>>(query, qA, M1 * EE);
    f32_to_bf16_k<<<3072, 256, 0, stream>>>(w_in, winb, 3 * EE * EE);
    f32_to_bf16_k<<<1024, 256, 0, stream>>>(w_out, woutb, EE * EE);
    erflip_k<<<256, 256, 0, stream>>>(relpos, erfp);

    // qkv projection: M=4096, N=3072, K=1024
    gemm_bt<<<(3072 / BNt) * (M1 / BMt), 256, 0, stream>>>(
        qA, winb, b_in, M1, 3072, EE, 0, q_ws, k_ws, v_ws, nullptr);

    transpose_v<<<BHC * 16, 256, 0, stream>>>(v_ws, vT_ws);

    attn_kernel<<<BHC * (SL / 16), 256, 0, stream>>>(q_ws, k_ws, vT_ws, erfp, O_flat);

    // out projection: M=4096, N=1024, K=1024
    gemm_bt<<<(1024 / BNt) * (M1 / BMt), 256, 0, stream>>>(
        O_flat, woutb, b_out, M1, 1024, EE, 1, nullptr, nullptr, nullptr, out);
}

// Round 2
// 353.002 us; speedup vs baseline: 1.1389x; 1.1389x over previous
//
#include <hip/hip_runtime.h>
#include <hip/hip_bf16.h>

// Problem constants (L=1024, B=4, E=1024, H=16, D=64)
#define SL 1024
#define BB 4
#define EE 1024
#define HH 16
#define DD 64
#define BHC 64          // BB*HH
#define M1 4096         // SL*BB

typedef __bf16 bf16x8 __attribute__((ext_vector_type(8)));
typedef __bf16 bf16x4 __attribute__((ext_vector_type(4)));
typedef float f32x4 __attribute__((ext_vector_type(4)));

__device__ __forceinline__ f32x4 mfma16(bf16x8 a, bf16x8 b, f32x4 c) {
    return __builtin_amdgcn_mfma_f32_16x16x32_bf16(a, b, c, 0, 0, 0);
}

// ---------------- conversion kernels ----------------
__global__ __launch_bounds__(256) void f32_to_bf16_k(const float* __restrict__ in,
                                                     __bf16* __restrict__ out, int n) {
    int idx = (blockIdx.x * 256 + threadIdx.x) * 4;
    if (idx >= n) return;
    float4 v = *(const float4*)&in[idx];
    bf16x4 o;
    o[0] = (__bf16)v.x; o[1] = (__bf16)v.y; o[2] = (__bf16)v.z; o[3] = (__bf16)v.w;
    *(bf16x4*)&out[idx] = o;
}

// erf[r][d] = relpos[1023-r][d], bf16
__global__ __launch_bounds__(256) void erflip_k(const float* __restrict__ rel,
                                                __bf16* __restrict__ erf) {
    int idx = blockIdx.x * 256 + threadIdx.x;   // 65536 total
    int r = idx >> 6, d = idx & 63;
    erf[idx] = (__bf16)rel[(1023 - r) * 64 + d];
}

// ---------------- GEMM: C = A(MxK) @ B(NxK)^T + bias ----------------
// mode 0: scatter to q/k/v bh-major bf16 (q scaled by 0.125)
// mode 1: plain fp32 store to outf (M x N)
#define BMt 128
#define BNt 128
#define BKt 32
#define LDK 40
__global__ __launch_bounds__(256) void gemm_bt(const __bf16* __restrict__ A,
                                               const __bf16* __restrict__ Bm,
                                               const float* __restrict__ bias,
                                               int M, int N, int K, int mode,
                                               __bf16* __restrict__ q_ws,
                                               __bf16* __restrict__ k_ws,
                                               __bf16* __restrict__ v_ws,
                                               float* __restrict__ outf) {
    __shared__ __bf16 As[BMt * LDK];
    __shared__ __bf16 Bs[BNt * LDK];
    int tid = threadIdx.x;
    int wave = tid >> 6, lane = tid & 63;
    int quad = lane >> 4, c = lane & 15;
    int ntiles = N / BNt;
    int bx = blockIdx.x % ntiles, by = blockIdx.x / ntiles;
    int m0 = by * BMt, n0 = bx * BNt;
    int wm = (wave >> 1) * 64, wn = (wave & 1) * 64;

    f32x4 acc[4][4] = {};
    for (int k0 = 0; k0 < K; k0 += BKt) {
        __syncthreads();
#pragma unroll
        for (int ch = 0; ch < 2; ++ch) {
            int p = tid + ch * 256;
            int row = p >> 2, col = (p & 3) * 8;
            *(bf16x8*)&As[row * LDK + col] = *(const bf16x8*)&A[(long)(m0 + row) * K + k0 + col];
            *(bf16x8*)&Bs[row * LDK + col] = *(const bf16x8*)&Bm[(long)(n0 + row) * K + k0 + col];
        }
        __syncthreads();
        bf16x8 af[4], bfr[4];
#pragma unroll
        for (int t = 0; t < 4; ++t) {
            af[t]  = *(const bf16x8*)&As[(wm + t * 16 + c) * LDK + quad * 8];
            bfr[t] = *(const bf16x8*)&Bs[(wn + t * 16 + c) * LDK + quad * 8];
        }
#pragma unroll
        for (int mt = 0; mt < 4; ++mt)
#pragma unroll
            for (int nt = 0; nt < 4; ++nt)
                acc[mt][nt] = mfma16(af[mt], bfr[nt], acc[mt][nt]);
    }
    // epilogue
#pragma unroll
    for (int mt = 0; mt < 4; ++mt) {
#pragma unroll
        for (int nt = 0; nt < 4; ++nt) {
            int nn = n0 + wn + nt * 16 + c;
            float bv = bias[nn];
#pragma unroll
            for (int i = 0; i < 4; ++i) {
                int mm = m0 + wm + mt * 16 + quad * 4 + i;
                float v = acc[mt][nt][i] + bv;
                if (mode == 0) {
                    int which = nn >> 10;
                    int cc = nn & 1023;
                    int h = cc >> 6, d = cc & 63;
                    int l = mm >> 2, b = mm & 3;
                    long off = ((long)(b * 16 + h) * 1024 + l) * 64 + d;
                    if (which == 0)      q_ws[off] = (__bf16)(v * 0.125f);
                    else if (which == 1) k_ws[off] = (__bf16)v;
                    else                 v_ws[off] = (__bf16)v;
                } else {
                    outf[(long)mm * N + nn] = v;
                }
            }
        }
    }
}

// ---------------- V transpose: [bh][m][d] -> [bh][d][m] ----------------
__global__ __launch_bounds__(256) void transpose_v(const __bf16* __restrict__ v_ws,
                                                   __bf16* __restrict__ vT_ws) {
    __shared__ __bf16 t[64 * 72];
    int bh = blockIdx.x >> 4, mt = blockIdx.x & 15;
    int tid = threadIdx.x;
    int r = tid >> 2, cg = (tid & 3) * 16;
    const __bf16* src = v_ws + ((long)bh * 1024 + mt * 64) * 64;
    *(bf16x8*)&t[r * 72 + cg]     = *(const bf16x8*)&src[r * 64 + cg];
    *(bf16x8*)&t[r * 72 + cg + 8] = *(const bf16x8*)&src[r * 64 + cg + 8];
    __syncthreads();
    __bf16 tmp[16] __attribute__((aligned(16)));
#pragma unroll
    for (int j = 0; j < 16; ++j) tmp[j] = t[(cg + j) * 72 + r];
    __bf16* dst = vT_ws + ((long)bh * 64 + r) * 1024 + mt * 64 + cg;
    *(bf16x8*)&dst[0] = *(const bf16x8*)&tmp[0];
    *(bf16x8*)&dst[8] = *(const bf16x8*)&tmp[8];
}

// ---------------- attention ----------------
// grid: 64 bh * 64 l-tiles; block 256 (4 waves). Wave w owns key cols [256w,256w+256).
// NOTE: every loop touching S[] is FULLY unrolled — partial unroll makes S[t]
// dynamically indexed -> compiler spills the whole array to scratch (round-1:
// 270 MB WRITE_SIZE of pure scratch traffic, 255us kernel).
#define LDP 1032
__global__ __launch_bounds__(256) void attn_kernel(const __bf16* __restrict__ q_ws,
                                                   const __bf16* __restrict__ k_ws,
                                                   const __bf16* __restrict__ vT_ws,
                                                   const __bf16* __restrict__ erf,
                                                   __bf16* __restrict__ O_flat) {
    __shared__ __bf16 RP[16 * LDP];      // R (rel) then reused for P
    __shared__ float smax[4][16];
    __shared__ float ssum[4][16];

    int tid = threadIdx.x;
    int w = tid >> 6, lane = tid & 63;
    int quad = lane >> 4, c = lane & 15;
    int bh = blockIdx.x >> 6;
    int l0 = (blockIdx.x & 63) * 16;
    int b = bh >> 4, h = bh & 15;

    const __bf16* qp = q_ws + ((long)bh * 1024 + l0) * 64;
    bf16x8 aq0 = *(const bf16x8*)&qp[c * 64 + quad * 8];
    bf16x8 aq1 = *(const bf16x8*)&qp[c * 64 + 32 + quad * 8];

    // Phase R: R[l][r] = q[l] . erf[r], r in [0, l0+15]
    for (int t = 0; t < 16; ++t) {
        int r0 = w * 256 + t * 16;
        if (r0 > l0 + 15) break;
        const __bf16* ep = erf + (long)r0 * 64;
        bf16x8 b0 = *(const bf16x8*)&ep[c * 64 + quad * 8];
        bf16x8 b1 = *(const bf16x8*)&ep[c * 64 + 32 + quad * 8];
        f32x4 ar = {0.f, 0.f, 0.f, 0.f};
        ar = mfma16(aq0, b0, ar);
        ar = mfma16(aq1, b1, ar);
#pragma unroll
        for (int i = 0; i < 4; ++i)
            RP[(quad * 4 + i) * LDP + r0 + c] = (__bf16)ar[i];
    }
    __syncthreads();

    // Phase S: scores = Q K^T + rel; running row-max folded in
    f32x4 S[16];
    float mx[4] = {-1e30f, -1e30f, -1e30f, -1e30f};
    const __bf16* kp = k_ws + (long)bh * 1024 * 64;
#pragma unroll
    for (int t = 0; t < 16; ++t) {
        int m0 = w * 256 + t * 16;
        bf16x8 b0 = *(const bf16x8*)&kp[(m0 + c) * 64 + quad * 8];
        bf16x8 b1 = *(const bf16x8*)&kp[(m0 + c) * 64 + 32 + quad * 8];
        f32x4 acc = {0.f, 0.f, 0.f, 0.f};
        acc = mfma16(aq0, b0, acc);
        acc = mfma16(aq1, b1, acc);
#pragma unroll
        for (int i = 0; i < 4; ++i) {
            int l = l0 + quad * 4 + i;
            int r = l - (m0 + c);
            if (r >= 0) acc[i] += (float)RP[(quad * 4 + i) * LDP + r];
            mx[i] = fmaxf(mx[i], acc[i]);
        }
        S[t] = acc;
    }

    // cross-lane + cross-wave row max (rows quad*4+i live in the 16 lanes of this quad)
    float gmax[4];
#pragma unroll
    for (int i = 0; i < 4; ++i) {
        float m = mx[i];
        for (int s = 1; s < 16; s <<= 1) m = fmaxf(m, __shfl_xor(m, s));
        mx[i] = m;
    }
    if (c == 0)
#pragma unroll
        for (int i = 0; i < 4; ++i) smax[w][quad * 4 + i] = mx[i];
    __syncthreads();
#pragma unroll
    for (int i = 0; i < 4; ++i)
        gmax[i] = fmaxf(fmaxf(smax[0][quad * 4 + i], smax[1][quad * 4 + i]),
                        fmaxf(smax[2][quad * 4 + i], smax[3][quad * 4 + i]));

    // P = exp(S - gmax); write to LDS (reuse R buffer; all R reads done at barrier above)
    float sum[4] = {0.f, 0.f, 0.f, 0.f};
#pragma unroll
    for (int t = 0; t < 16; ++t) {
        int m0 = w * 256 + t * 16;
        f32x4 p;
#pragma unroll
        for (int i = 0; i < 4; ++i) {
            p[i] = __expf(S[t][i] - gmax[i]);
            sum[i] += p[i];
        }
#pragma unroll
        for (int i = 0; i < 4; ++i)
            RP[(quad * 4 + i) * LDP + m0 + c] = (__bf16)p[i];
    }
#pragma unroll
    for (int i = 0; i < 4; ++i)
        for (int s = 1; s < 16; s <<= 1) sum[i] += __shfl_xor(sum[i], s);
    if (c == 0)
#pragma unroll
        for (int i = 0; i < 4; ++i) ssum[w][quad * 4 + i] = sum[i];
    __syncthreads();
    float rs[4];
#pragma unroll
    for (int i = 0; i < 4; ++i) {
        float g = ssum[0][quad * 4 + i] + ssum[1][quad * 4 + i] +
                  ssum[2][quad * 4 + i] + ssum[3][quad * 4 + i];
        rs[i] = 1.0f / g;
    }

    // Phase PV: wave w computes d-tile w (16 d cols), contracting over all 1024 m
    f32x4 o = {0.f, 0.f, 0.f, 0.f};
    const __bf16* vp = vT_ws + (long)bh * 64 * 1024 + (long)(w * 16 + c) * 1024;
#pragma unroll 8
    for (int ks = 0; ks < 32; ++ks) {
        bf16x8 pa = *(const bf16x8*)&RP[c * LDP + ks * 32 + quad * 8];
        bf16x8 vb = *(const bf16x8*)&vp[ks * 32 + quad * 8];
        o = mfma16(pa, vb, o);
    }
#pragma unroll
    for (int i = 0; i < 4; ++i) {
        int l = l0 + quad * 4 + i;
        long row = (long)l * 4 + b;
        int col = h * 64 + w * 16 + c;
        O_flat[row * 1024 + col] = (__bf16)(o[i] * rs[i]);
    }
}

// ---------------- launch ----------------
extern "C" void kernel_launch(void* const* d_in, const int* in_sizes, int n_in,
                              void* d_out, int out_size, void* d_ws, size_t ws_size,
                              hipStream_t stream) {
    const float* query  = (const float*)d_in[0];
    const float* relpos = (const float*)d_in[1];
    const float* w_in   = (const float*)d_in[2];
    const float* b_in   = (const float*)d_in[3];
    const float* w_out  = (const float*)d_in[4];
    const float* b_out  = (const float*)d_in[5];
    float* out = (float*)d_out;

    char* ws = (char*)d_ws;
    size_t off = 0;
    auto alloc = [&](size_t bytes) {
        void* p = ws + off;
        off += (bytes + 255) & ~(size_t)255;
        return p;
    };
    __bf16* qA    = (__bf16*)alloc((size_t)M1 * EE * 2);        // query bf16
    __bf16* winb  = (__bf16*)alloc((size_t)3 * EE * EE * 2);    // in_proj_weight bf16
    __bf16* woutb = (__bf16*)alloc((size_t)EE * EE * 2);        // out_proj_weight bf16
    __bf16* erfp  = (__bf16*)alloc((size_t)SL * DD * 2);        // flipped er bf16
    __bf16* q_ws  = (__bf16*)alloc((size_t)BHC * SL * DD * 2);
    __bf16* k_ws  = (__bf16*)alloc((size_t)BHC * SL * DD * 2);
    __bf16* v_ws  = (__bf16*)alloc((size_t)BHC * SL * DD * 2);
    __bf16* vT_ws = (__bf16*)alloc((size_t)BHC * SL * DD * 2);
    __bf16* O_flat= (__bf16*)alloc((size_t)M1 * EE * 2);

    f32_to_bf16_k<<<4096, 256, 0, stream>>>(query, qA, M1 * EE);
    f32_to_bf16_k<<<3072, 256, 0, stream>>>(w_in, winb, 3 * EE * EE);
    f32_to_bf16_k<<<1024, 256, 0, stream>>>(w_out, woutb, EE * EE);
    erflip_k<<<256, 256, 0, stream>>>(relpos, erfp);

    // qkv projection: M=4096, N=3072, K=1024
    gemm_bt<<<(3072 / BNt) * (M1 / BMt), 256, 0, stream>>>(
        qA, winb, b_in, M1, 3072, EE, 0, q_ws, k_ws, v_ws, nullptr);

    transpose_v<<<BHC * 16, 256, 0, stream>>>(v_ws, vT_ws);

    attn_kernel<<<BHC * (SL / 16), 256, 0, stream>>>(q_ws, k_ws, vT_ws, erfp, O_flat);

    // out projection: M=4096, N=1024, K=1024
    gemm_bt<<<(1024 / BNt) * (M1 / BMt), 256, 0, stream>>>(
        O_flat, woutb, b_out, M1, 1024, EE, 1, nullptr, nullptr, nullptr, out);
}

// Round 3
// 337.414 us; speedup vs baseline: 1.1915x; 1.0462x over previous
//
#include <hip/hip_runtime.h>
#include <hip/hip_bf16.h>

// Problem constants (L=1024, B=4, E=1024, H=16, D=64)
#define SL 1024
#define BB 4
#define EE 1024
#define HH 16
#define DD 64
#define BHC 64          // BB*HH
#define M1 4096         // SL*BB

typedef __bf16 bf16x8 __attribute__((ext_vector_type(8)));
typedef __bf16 bf16x4 __attribute__((ext_vector_type(4)));
typedef float f32x4 __attribute__((ext_vector_type(4)));

__device__ __forceinline__ f32x4 mfma16(bf16x8 a, bf16x8 b, f32x4 c) {
    return __builtin_amdgcn_mfma_f32_16x16x32_bf16(a, b, c, 0, 0, 0);
}

// ---------------- conversion kernels ----------------
__global__ __launch_bounds__(256) void f32_to_bf16_k(const float* __restrict__ in,
                                                     __bf16* __restrict__ out, int n) {
    int idx = (blockIdx.x * 256 + threadIdx.x) * 4;
    if (idx >= n) return;
    float4 v = *(const float4*)&in[idx];
    bf16x4 o;
    o[0] = (__bf16)v.x; o[1] = (__bf16)v.y; o[2] = (__bf16)v.z; o[3] = (__bf16)v.w;
    *(bf16x4*)&out[idx] = o;
}

// erf[r][d] = relpos[1023-r][d], bf16
__global__ __launch_bounds__(256) void erflip_k(const float* __restrict__ rel,
                                                __bf16* __restrict__ erf) {
    int idx = blockIdx.x * 256 + threadIdx.x;   // 65536 total
    int r = idx >> 6, d = idx & 63;
    erf[idx] = (__bf16)rel[(1023 - r) * 64 + d];
}

// ---------------- GEMM: C = A(MxK) @ B(NxK)^T + bias ----------------
// mode 0: scatter to q/k/v bh-major bf16 (q scaled by 0.125)
// mode 1: plain fp32 store to outf (M x N)
#define BMt 128
#define BNt 128
#define BKt 32
#define LDK 40
__global__ __launch_bounds__(256) void gemm_bt(const __bf16* __restrict__ A,
                                               const __bf16* __restrict__ Bm,
                                               const float* __restrict__ bias,
                                               int M, int N, int K, int mode,
                                               __bf16* __restrict__ q_ws,
                                               __bf16* __restrict__ k_ws,
                                               __bf16* __restrict__ v_ws,
                                               float* __restrict__ outf) {
    __shared__ __bf16 As[BMt * LDK];
    __shared__ __bf16 Bs[BNt * LDK];
    int tid = threadIdx.x;
    int wave = tid >> 6, lane = tid & 63;
    int quad = lane >> 4, c = lane & 15;
    int ntiles = N / BNt;
    int bx = blockIdx.x % ntiles, by = blockIdx.x / ntiles;
    int m0 = by * BMt, n0 = bx * BNt;
    int wm = (wave >> 1) * 64, wn = (wave & 1) * 64;

    f32x4 acc[4][4] = {};
    for (int k0 = 0; k0 < K; k0 += BKt) {
        __syncthreads();
#pragma unroll
        for (int ch = 0; ch < 2; ++ch) {
            int p = tid + ch * 256;
            int row = p >> 2, col = (p & 3) * 8;
            *(bf16x8*)&As[row * LDK + col] = *(const bf16x8*)&A[(long)(m0 + row) * K + k0 + col];
            *(bf16x8*)&Bs[row * LDK + col] = *(const bf16x8*)&Bm[(long)(n0 + row) * K + k0 + col];
        }
        __syncthreads();
        bf16x8 af[4], bfr[4];
#pragma unroll
        for (int t = 0; t < 4; ++t) {
            af[t]  = *(const bf16x8*)&As[(wm + t * 16 + c) * LDK + quad * 8];
            bfr[t] = *(const bf16x8*)&Bs[(wn + t * 16 + c) * LDK + quad * 8];
        }
#pragma unroll
        for (int mt = 0; mt < 4; ++mt)
#pragma unroll
            for (int nt = 0; nt < 4; ++nt)
                acc[mt][nt] = mfma16(af[mt], bfr[nt], acc[mt][nt]);
    }
    // epilogue
#pragma unroll
    for (int mt = 0; mt < 4; ++mt) {
#pragma unroll
        for (int nt = 0; nt < 4; ++nt) {
            int nn = n0 + wn + nt * 16 + c;
            float bv = bias[nn];
#pragma unroll
            for (int i = 0; i < 4; ++i) {
                int mm = m0 + wm + mt * 16 + quad * 4 + i;
                float v = acc[mt][nt][i] + bv;
                if (mode == 0) {
                    int which = nn >> 10;
                    int cc = nn & 1023;
                    int h = cc >> 6, d = cc & 63;
                    int l = mm >> 2, b = mm & 3;
                    long off = ((long)(b * 16 + h) * 1024 + l) * 64 + d;
                    if (which == 0)      q_ws[off] = (__bf16)(v * 0.125f);
                    else if (which == 1) k_ws[off] = (__bf16)v;
                    else                 v_ws[off] = (__bf16)v;
                } else {
                    outf[(long)mm * N + nn] = v;
                }
            }
        }
    }
}

// ---------------- V transpose: [bh][m][d] -> [bh][d][m] ----------------
__global__ __launch_bounds__(256) void transpose_v(const __bf16* __restrict__ v_ws,
                                                   __bf16* __restrict__ vT_ws) {
    __shared__ __bf16 t[64 * 72];
    int bh = blockIdx.x >> 4, mt = blockIdx.x & 15;
    int tid = threadIdx.x;
    int r = tid >> 2, cg = (tid & 3) * 16;
    const __bf16* src = v_ws + ((long)bh * 1024 + mt * 64) * 64;
    *(bf16x8*)&t[r * 72 + cg]     = *(const bf16x8*)&src[r * 64 + cg];
    *(bf16x8*)&t[r * 72 + cg + 8] = *(const bf16x8*)&src[r * 64 + cg + 8];
    __syncthreads();
    __bf16 tmp[16] __attribute__((aligned(16)));
#pragma unroll
    for (int j = 0; j < 16; ++j) tmp[j] = t[(cg + j) * 72 + r];
    __bf16* dst = vT_ws + ((long)bh * 64 + r) * 1024 + mt * 64 + cg;
    *(bf16x8*)&dst[0] = *(const bf16x8*)&tmp[0];
    *(bf16x8*)&dst[8] = *(const bf16x8*)&tmp[8];
}

// ---------------- attention (flash-style, wave-independent) ----------------
// grid: 64 bh * 16 q-tiles-of-64; block 256 = 4 waves; wave w owns Q rows
// [lt*64+16w, lt*64+16w+16) and iterates ALL 16 key tiles of 64 with online
// softmax. rel term: r = l - m shifts by -64 per key tile, so each wave needs
// at most 2 rel r-tiles per iteration, one of them new -> 2-slot LDS ring
// computed AND read only by this wave. P->A-layout round-trip also per-wave.
// => ZERO __syncthreads(); waves hide each other's latencies.
__global__ __launch_bounds__(256, 4) void attn_kernel(const __bf16* __restrict__ q_ws,
                                                      const __bf16* __restrict__ k_ws,
                                                      const __bf16* __restrict__ vT_ws,
                                                      const __bf16* __restrict__ erf,
                                                      __bf16* __restrict__ O_flat) {
    // per-wave region: R ring slot0 [0,1152), slot1 [1152,2304), P [2304,3456)
    __shared__ __bf16 lds[4][3 * 16 * 72];

    int tid = threadIdx.x;
    int w = tid >> 6, lane = tid & 63;
    int q = lane >> 4, c = lane & 15;
    int bh = blockIdx.x >> 4;
    int lt = blockIdx.x & 15;
    int b = bh >> 4, h = bh & 15;
    int l0w = lt * 64 + w * 16;

    __bf16* RW = &lds[w][0];
    __bf16* PW = &lds[w][2304];

    const __bf16* qp = q_ws + ((long)bh * 1024 + l0w) * 64;
    bf16x8 aq0 = *(const bf16x8*)&qp[c * 64 + q * 8];
    bf16x8 aq1 = *(const bf16x8*)&qp[c * 64 + 32 + q * 8];

    f32x4 O[4] = {};                                 // 4 d-sub-tiles (16 cols each)
    float m_run[4] = {-1e30f, -1e30f, -1e30f, -1e30f};
    float l_run[4] = {0.f, 0.f, 0.f, 0.f};

    const __bf16* kbase = k_ws + (long)bh * 1024 * 64;
    const __bf16* vbase = vT_ws + (long)bh * 64 * 1024;

    for (int kt = 15; kt >= 0; --kt) {
        // ---- new rel tile j = lt-kt (block-uniform branch) ----
        if (kt <= lt) {
            int j = lt - kt;
            __bf16* rt = RW + (j & 1) * 1152;
            const __bf16* ep = erf + (long)j * 64 * 64;
#pragma unroll
            for (int s = 0; s < 4; ++s) {
                bf16x8 eb0 = *(const bf16x8*)&ep[(16 * s + c) * 64 + q * 8];
                bf16x8 eb1 = *(const bf16x8*)&ep[(16 * s + c) * 64 + 32 + q * 8];
                f32x4 ar = {0.f, 0.f, 0.f, 0.f};
                ar = mfma16(aq0, eb0, ar);
                ar = mfma16(aq1, eb1, ar);
#pragma unroll
                for (int i = 0; i < 4; ++i)
                    rt[(q * 4 + i) * 72 + 16 * s + c] = (__bf16)ar[i];
            }
        }
        // ---- S = Q K^T (16 x 64) ----
        const __bf16* kp = kbase + (long)kt * 64 * 64;
        f32x4 S[4];
#pragma unroll
        for (int s = 0; s < 4; ++s) {
            bf16x8 kb0 = *(const bf16x8*)&kp[(16 * s + c) * 64 + q * 8];
            bf16x8 kb1 = *(const bf16x8*)&kp[(16 * s + c) * 64 + 32 + q * 8];
            f32x4 acc = {0.f, 0.f, 0.f, 0.f};
            acc = mfma16(aq0, kb0, acc);
            acc = mfma16(aq1, kb1, acc);
            S[s] = acc;
        }
        // ---- rel gather: r = l - m; slot = (r>>6)&1 holds r-tile r>>6 ----
        if (kt <= lt) {
            int gq = (lt - kt) * 64 + w * 16 + q * 4 - c;   // r = gq + i - 16s
#pragma unroll
            for (int s = 0; s < 4; ++s)
#pragma unroll
                for (int i = 0; i < 4; ++i) {
                    int rf = gq + i - 16 * s;
                    if (rf >= 0)
                        S[s][i] += (float)RW[((rf >> 6) & 1) * 1152 + (q * 4 + i) * 72 + (rf & 63)];
                }
        }
        // ---- online softmax update ----
        float alpha[4];
#pragma unroll
        for (int i = 0; i < 4; ++i) {
            float t = fmaxf(fmaxf(S[0][i], S[1][i]), fmaxf(S[2][i], S[3][i]));
#pragma unroll
            for (int sh = 1; sh < 16; sh <<= 1) t = fmaxf(t, __shfl_xor(t, sh));
            float nm = fmaxf(m_run[i], t);
            alpha[i] = __expf(m_run[i] - nm);
            m_run[i] = nm;
        }
        float tsum[4] = {0.f, 0.f, 0.f, 0.f};
#pragma unroll
        for (int s = 0; s < 4; ++s)
#pragma unroll
            for (int i = 0; i < 4; ++i) {
                float p = __expf(S[s][i] - m_run[i]);
                S[s][i] = p;
                tsum[i] += p;
            }
#pragma unroll
        for (int i = 0; i < 4; ++i) {
#pragma unroll
            for (int sh = 1; sh < 16; sh <<= 1) tsum[i] += __shfl_xor(tsum[i], sh);
            l_run[i] = l_run[i] * alpha[i] + tsum[i];
        }
        // ---- P to LDS (C-layout scatter), rescale O ----
#pragma unroll
        for (int s = 0; s < 4; ++s)
#pragma unroll
            for (int i = 0; i < 4; ++i)
                PW[(q * 4 + i) * 72 + 16 * s + c] = (__bf16)S[s][i];
#pragma unroll
        for (int s = 0; s < 4; ++s)
#pragma unroll
            for (int i = 0; i < 4; ++i)
                O[s][i] *= alpha[i];
        // ---- O += P V ----
        bf16x8 pa0 = *(const bf16x8*)&PW[c * 72 + q * 8];
        bf16x8 pa1 = *(const bf16x8*)&PW[c * 72 + 32 + q * 8];
#pragma unroll
        for (int s = 0; s < 4; ++s) {
            const __bf16* vp = vbase + (long)(16 * s + c) * 1024 + kt * 64;
            bf16x8 vb0 = *(const bf16x8*)&vp[q * 8];
            bf16x8 vb1 = *(const bf16x8*)&vp[32 + q * 8];
            O[s] = mfma16(pa0, vb0, O[s]);
            O[s] = mfma16(pa1, vb1, O[s]);
        }
    }
    // ---- epilogue: normalize, store ----
#pragma unroll
    for (int i = 0; i < 4; ++i) {
        float rs = 1.0f / l_run[i];
        int l = l0w + q * 4 + i;
        long row = (long)l * 4 + b;
#pragma unroll
        for (int s = 0; s < 4; ++s)
            O_flat[row * 1024 + h * 64 + 16 * s + c] = (__bf16)(O[s][i] * rs);
    }
}

// ---------------- launch ----------------
extern "C" void kernel_launch(void* const* d_in, const int* in_sizes, int n_in,
                              void* d_out, int out_size, void* d_ws, size_t ws_size,
                              hipStream_t stream) {
    const float* query  = (const float*)d_in[0];
    const float* relpos = (const float*)d_in[1];
    const float* w_in   = (const float*)d_in[2];
    const float* b_in   = (const float*)d_in[3];
    const float* w_out  = (const float*)d_in[4];
    const float* b_out  = (const float*)d_in[5];
    float* out = (float*)d_out;

    char* ws = (char*)d_ws;
    size_t off = 0;
    auto alloc = [&](size_t bytes) {
        void* p = ws + off;
        off += (bytes + 255) & ~(size_t)255;
        return p;
    };
    __bf16* qA    = (__bf16*)alloc((size_t)M1 * EE * 2);        // query bf16
    __bf16* winb  = (__bf16*)alloc((size_t)3 * EE * EE * 2);    // in_proj_weight bf16
    __bf16* woutb = (__bf16*)alloc((size_t)EE * EE * 2);        // out_proj_weight bf16
    __bf16* erfp  = (__bf16*)alloc((size_t)SL * DD * 2);        // flipped er bf16
    __bf16* q_ws  = (__bf16*)alloc((size_t)BHC * SL * DD * 2);
    __bf16* k_ws  = (__bf16*)alloc((size_t)BHC * SL * DD * 2);
    __bf16* v_ws  = (__bf16*)alloc((size_t)BHC * SL * DD * 2);
    __bf16* vT_ws = (__bf16*)alloc((size_t)BHC * SL * DD * 2);
    __bf16* O_flat= (__bf16*)alloc((size_t)M1 * EE * 2);

    f32_to_bf16_k<<<4096, 256, 0, stream>>>(query, qA, M1 * EE);
    f32_to_bf16_k<<<3072, 256, 0, stream>>>(w_in, winb, 3 * EE * EE);
    f32_to_bf16_k<<<1024, 256, 0, stream>>>(w_out, woutb, EE * EE);
    erflip_k<<<256, 256, 0, stream>>>(relpos, erfp);

    // qkv projection: M=4096, N=3072, K=1024
    gemm_bt<<<(3072 / BNt) * (M1 / BMt), 256, 0, stream>>>(
        qA, winb, b_in, M1, 3072, EE, 0, q_ws, k_ws, v_ws, nullptr);

    transpose_v<<<BHC * 16, 256, 0, stream>>>(v_ws, vT_ws);

    attn_kernel<<<BHC * 16, 256, 0, stream>>>(q_ws, k_ws, vT_ws, erfp, O_flat);

    // out projection: M=4096, N=1024, K=1024
    gemm_bt<<<(1024 / BNt) * (M1 / BMt), 256, 0, stream>>>(
        O_flat, woutb, b_out, M1, 1024, EE, 1, nullptr, nullptr, nullptr, out);
}

// Round 4
// 302.610 us; speedup vs baseline: 1.3286x; 1.1150x over previous
//
#include <hip/hip_runtime.h>
#include <hip/hip_bf16.h>

// Problem constants (L=1024, B=4, E=1024, H=16, D=64)
#define SL 1024
#define BB 4
#define EE 1024
#define HH 16
#define DD 64
#define BHC 64          // BB*HH
#define M1 4096         // SL*BB

typedef __bf16 bf16x8 __attribute__((ext_vector_type(8)));
typedef __bf16 bf16x4 __attribute__((ext_vector_type(4)));
typedef float f32x4 __attribute__((ext_vector_type(4)));

__device__ __forceinline__ f32x4 mfma16(bf16x8 a, bf16x8 b, f32x4 c) {
    return __builtin_amdgcn_mfma_f32_16x16x32_bf16(a, b, c, 0, 0, 0);
}

// ---------------- conversion kernels ----------------
__global__ __launch_bounds__(256) void f32_to_bf16_k(const float* __restrict__ in,
                                                     __bf16* __restrict__ out, int n) {
    int idx = (blockIdx.x * 256 + threadIdx.x) * 4;
    if (idx >= n) return;
    float4 v = *(const float4*)&in[idx];
    bf16x4 o;
    o[0] = (__bf16)v.x; o[1] = (__bf16)v.y; o[2] = (__bf16)v.z; o[3] = (__bf16)v.w;
    *(bf16x4*)&out[idx] = o;
}

// erf[r][d] = relpos[1023-r][d], bf16
__global__ __launch_bounds__(256) void erflip_k(const float* __restrict__ rel,
                                                __bf16* __restrict__ erf) {
    int idx = blockIdx.x * 256 + threadIdx.x;   // 65536 total
    int r = idx >> 6, d = idx & 63;
    erf[idx] = (__bf16)rel[(1023 - r) * 64 + d];
}

// ---------------- GEMM: C = A(MxK) @ B(NxK)^T + bias ----------------
// mode 0: scatter to q/k/v bh-major bf16 (q scaled by 0.125)
// mode 1: plain fp32 store to outf (M x N)
#define BMt 128
#define BNt 128
#define BKt 32
#define LDK 40
__global__ __launch_bounds__(256) void gemm_bt(const __bf16* __restrict__ A,
                                               const __bf16* __restrict__ Bm,
                                               const float* __restrict__ bias,
                                               int M, int N, int K, int mode,
                                               __bf16* __restrict__ q_ws,
                                               __bf16* __restrict__ k_ws,
                                               __bf16* __restrict__ v_ws,
                                               float* __restrict__ outf) {
    __shared__ __bf16 As[BMt * LDK];
    __shared__ __bf16 Bs[BNt * LDK];
    int tid = threadIdx.x;
    int wave = tid >> 6, lane = tid & 63;
    int quad = lane >> 4, c = lane & 15;
    int ntiles = N / BNt;
    int bx = blockIdx.x % ntiles, by = blockIdx.x / ntiles;
    int m0 = by * BMt, n0 = bx * BNt;
    int wm = (wave >> 1) * 64, wn = (wave & 1) * 64;

    f32x4 acc[4][4] = {};
    for (int k0 = 0; k0 < K; k0 += BKt) {
        __syncthreads();
#pragma unroll
        for (int ch = 0; ch < 2; ++ch) {
            int p = tid + ch * 256;
            int row = p >> 2, col = (p & 3) * 8;
            *(bf16x8*)&As[row * LDK + col] = *(const bf16x8*)&A[(long)(m0 + row) * K + k0 + col];
            *(bf16x8*)&Bs[row * LDK + col] = *(const bf16x8*)&Bm[(long)(n0 + row) * K + k0 + col];
        }
        __syncthreads();
        bf16x8 af[4], bfr[4];
#pragma unroll
        for (int t = 0; t < 4; ++t) {
            af[t]  = *(const bf16x8*)&As[(wm + t * 16 + c) * LDK + quad * 8];
            bfr[t] = *(const bf16x8*)&Bs[(wn + t * 16 + c) * LDK + quad * 8];
        }
#pragma unroll
        for (int mt = 0; mt < 4; ++mt)
#pragma unroll
            for (int nt = 0; nt < 4; ++nt)
                acc[mt][nt] = mfma16(af[mt], bfr[nt], acc[mt][nt]);
    }
    // epilogue
#pragma unroll
    for (int mt = 0; mt < 4; ++mt) {
#pragma unroll
        for (int nt = 0; nt < 4; ++nt) {
            int nn = n0 + wn + nt * 16 + c;
            float bv = bias[nn];
#pragma unroll
            for (int i = 0; i < 4; ++i) {
                int mm = m0 + wm + mt * 16 + quad * 4 + i;
                float v = acc[mt][nt][i] + bv;
                if (mode == 0) {
                    int which = nn >> 10;
                    int cc = nn & 1023;
                    int h = cc >> 6, d = cc & 63;
                    int l = mm >> 2, b = mm & 3;
                    long off = ((long)(b * 16 + h) * 1024 + l) * 64 + d;
                    if (which == 0)      q_ws[off] = (__bf16)(v * 0.125f);
                    else if (which == 1) k_ws[off] = (__bf16)v;
                    else                 v_ws[off] = (__bf16)v;
                } else {
                    outf[(long)mm * N + nn] = v;
                }
            }
        }
    }
}

// ---------------- V transpose: [bh][m][d] -> [bh][d][m] ----------------
__global__ __launch_bounds__(256) void transpose_v(const __bf16* __restrict__ v_ws,
                                                   __bf16* __restrict__ vT_ws) {
    __shared__ __bf16 t[64 * 72];
    int bh = blockIdx.x >> 4, mt = blockIdx.x & 15;
    int tid = threadIdx.x;
    int r = tid >> 2, cg = (tid & 3) * 16;
    const __bf16* src = v_ws + ((long)bh * 1024 + mt * 64) * 64;
    *(bf16x8*)&t[r * 72 + cg]     = *(const bf16x8*)&src[r * 64 + cg];
    *(bf16x8*)&t[r * 72 + cg + 8] = *(const bf16x8*)&src[r * 64 + cg + 8];
    __syncthreads();
    __bf16 tmp[16] __attribute__((aligned(16)));
#pragma unroll
    for (int j = 0; j < 16; ++j) tmp[j] = t[(cg + j) * 72 + r];
    __bf16* dst = vT_ws + ((long)bh * 64 + r) * 1024 + mt * 64 + cg;
    *(bf16x8*)&dst[0] = *(const bf16x8*)&tmp[0];
    *(bf16x8*)&dst[8] = *(const bf16x8*)&tmp[8];
}

// ---------------- attention (transposed-S flash, K-staged, XCD-swizzled) ----
// grid 1024 blocks (64 bh x 16 l-tiles), block 256 = 4 waves, wave owns 16 Q
// rows. S^T = K*Q^T so each lane owns ONE row (l = l0w + c): scalar softmax
// state, 2-step shfl reductions, per-round sum reduction eliminated.
// K tile (64 keys) staged to LDS (reg->LDS, double-buffered, prefetched a
// full round ahead) so the 4 waves share one global read and the load is off
// the dependent chain. V/erf read direct (L2-hot w/ XCD swizzle).
#define KST 72   // Kbuf row stride (halfwords), 144 B: 16B-aligned frags, 2-way banks
#define RST 68   // rel-ring row stride
#define PST 72   // P row stride
__global__ __launch_bounds__(256, 3) void attn_kernel(const __bf16* __restrict__ q_ws,
                                                      const __bf16* __restrict__ k_ws,
                                                      const __bf16* __restrict__ vT_ws,
                                                      const __bf16* __restrict__ erf,
                                                      __bf16* __restrict__ O_flat) {
    __shared__ __bf16 Kb[2][64 * KST];        // 18432 B
    __shared__ __bf16 Ring[4][2 * 16 * RST];  // 17408 B (per-wave 2-slot rel ring)
    __shared__ __bf16 Pb[4][16 * PST];        // 9216 B  (per-wave P round-trip)

    int tid = threadIdx.x;
    int w = tid >> 6, lane = tid & 63;
    int q = lane >> 4, c = lane & 15;
    // XCD-localized swizzle: XCD x (= bid%8 round-robin) gets bh in [8x, 8x+8)
    // so each XCD's L2 holds a ~2MB K/V slice instead of thrashing all 16MB.
    int bid = blockIdx.x;
    int x = bid & 7, ii = bid >> 3;
    int bh = x * 8 + (ii >> 4);
    int lt = ii & 15;
    int b = bh >> 4, h = bh & 15;
    int l0w = lt * 64 + w * 16;

    __bf16* RW = Ring[w];
    __bf16* PW = Pb[w];

    const __bf16* qp = q_ws + ((long)bh * 1024 + l0w) * 64;
    bf16x8 qf0 = *(const bf16x8*)&qp[c * 64 + q * 8];
    bf16x8 qf1 = *(const bf16x8*)&qp[c * 64 + 32 + q * 8];

    const __bf16* kbase = k_ws + (long)bh * 65536;
    const __bf16* vbase = vT_ws + (long)bh * 65536;

    // prologue: stage K tile 15 into parity 1 (f = n*256+tid -> row f>>3, 16B chunk f&7)
#pragma unroll
    for (int n = 0; n < 2; ++n) {
        int f = n * 256 + tid;
        int r = f >> 3, ch = f & 7;
        *(bf16x8*)&Kb[1][r * KST + ch * 8] =
            *(const bf16x8*)&kbase[(15 * 64 + r) * 64 + ch * 8];
    }
    __syncthreads();

    f32x4 O[4] = {};
    float m_run = -1e30f, l_run = 0.f;
    int rowr = l0w + c;        // this lane's l; rel index r = rowr - m

    for (int kt = 15; kt >= 0; --kt) {
        const __bf16* Kc = Kb[kt & 1];
        // ---- prefetch next K tile into regs (committed to LDS at round end) ----
        bf16x8 st0, st1;
        int pr0, pc0, pr1, pc1;
        if (kt > 0) {
            int f0 = tid, f1 = 256 + tid;
            pr0 = f0 >> 3; pc0 = f0 & 7; pr1 = f1 >> 3; pc1 = f1 & 7;
            const __bf16* kt0 = kbase + (kt - 1) * 4096;
            st0 = *(const bf16x8*)&kt0[pr0 * 64 + pc0 * 8];
            st1 = *(const bf16x8*)&kt0[pr1 * 64 + pc1 * 8];
        }
        // ---- R phase: new rel tile j = lt-kt (R^T = erf * Q^T) ----
        int j = lt - kt;
        if (j >= 0) {
            const __bf16* ep = erf + (long)j * 4096;
            __bf16* rt = RW + (j & 1) * (16 * RST);
#pragma unroll
            for (int s = 0; s < 4; ++s) {
                bf16x8 ea0 = *(const bf16x8*)&ep[(16 * s + c) * 64 + q * 8];
                bf16x8 ea1 = *(const bf16x8*)&ep[(16 * s + c) * 64 + 32 + q * 8];
                f32x4 ar = {0.f, 0.f, 0.f, 0.f};
                ar = mfma16(ea0, qf0, ar);
                ar = mfma16(ea1, qf1, ar);
                bf16x4 pk;
#pragma unroll
                for (int i = 0; i < 4; ++i) pk[i] = (__bf16)ar[i];
                *(bf16x4*)&rt[c * RST + 16 * s + 4 * q] = pk;   // row l=c, r-local 16s+4q+i
            }
        }
        // ---- S^T = K Q^T: lane(q,c) gets S[m = kt*64+16s+4q+i][l = l0w+c] ----
        f32x4 S[4];
#pragma unroll
        for (int s = 0; s < 4; ++s) {
            bf16x8 ka0 = *(const bf16x8*)&Kc[(16 * s + c) * KST + q * 8];
            bf16x8 ka1 = *(const bf16x8*)&Kc[(16 * s + c) * KST + 32 + q * 8];
            f32x4 acc = {0.f, 0.f, 0.f, 0.f};
            acc = mfma16(ka0, qf0, acc);
            acc = mfma16(ka1, qf1, acc);
            S[s] = acc;
        }
        // ---- rel gather: r = rowr - m; tiles {j-1, j} live in the 2-slot ring ----
        if (j >= 0) {
            int rb = rowr - kt * 64 - 4 * q;
#pragma unroll
            for (int s = 0; s < 4; ++s)
#pragma unroll
                for (int i = 0; i < 4; ++i) {
                    int r = rb - 16 * s - i;
                    if (r >= 0)
                        S[s][i] += (float)RW[((r >> 6) & 1) * (16 * RST) + c * RST + (r & 63)];
                }
        }
        // ---- online softmax (row l = c is lane-local => scalar state) ----
        float t = S[0][0];
#pragma unroll
        for (int s = 0; s < 4; ++s)
#pragma unroll
            for (int i = 0; i < 4; ++i) t = fmaxf(t, S[s][i]);
        t = fmaxf(t, __shfl_xor(t, 16));
        t = fmaxf(t, __shfl_xor(t, 32));
        float nm = fmaxf(m_run, t);
        float alpha = __expf(m_run - nm);
        m_run = nm;
        float ts = 0.f;
#pragma unroll
        for (int s = 0; s < 4; ++s)
#pragma unroll
            for (int i = 0; i < 4; ++i) {
                float p = __expf(S[s][i] - nm);
                S[s][i] = p;
                ts += p;
            }
        l_run = l_run * alpha + ts;   // lane-partial; cross-lane sum once in epilogue
        // ---- P to LDS (b64 packed), rescale O ----
#pragma unroll
        for (int s = 0; s < 4; ++s) {
            bf16x4 pk;
#pragma unroll
            for (int i = 0; i < 4; ++i) pk[i] = (__bf16)S[s][i];
            *(bf16x4*)&PW[c * PST + 16 * s + 4 * q] = pk;
        }
#pragma unroll
        for (int s = 0; s < 4; ++s)
#pragma unroll
            for (int i = 0; i < 4; ++i) O[s][i] *= alpha;
        // ---- O^T += V^T P^T ----
        bf16x8 pa0 = *(const bf16x8*)&PW[c * PST + q * 8];
        bf16x8 pa1 = *(const bf16x8*)&PW[c * PST + 32 + q * 8];
#pragma unroll
        for (int s = 0; s < 4; ++s) {
            const __bf16* vp = vbase + (long)(16 * s + c) * 1024 + kt * 64;
            bf16x8 va0 = *(const bf16x8*)&vp[q * 8];
            bf16x8 va1 = *(const bf16x8*)&vp[32 + q * 8];
            O[s] = mfma16(va0, pa0, O[s]);
            O[s] = mfma16(va1, pa1, O[s]);
        }
        // ---- commit staged K tile, sync ----
        if (kt > 0) {
            __bf16* Kn = Kb[(kt - 1) & 1];
            *(bf16x8*)&Kn[pr0 * KST + pc0 * 8] = st0;
            *(bf16x8*)&Kn[pr1 * KST + pc1 * 8] = st1;
        }
        __syncthreads();
    }
    // ---- epilogue: finish denominator across the 4 q-lanes of each row ----
    float tot = l_run;
    tot += __shfl_xor(tot, 16);
    tot += __shfl_xor(tot, 32);
    float rs = 1.0f / tot;
    long row = (long)(l0w + c) * 4 + b;
#pragma unroll
    for (int s = 0; s < 4; ++s) {
        bf16x4 ov;
#pragma unroll
        for (int i = 0; i < 4; ++i) ov[i] = (__bf16)(O[s][i] * rs);
        *(bf16x4*)&O_flat[row * 1024 + h * 64 + 16 * s + 4 * q] = ov;
    }
}

// ---------------- launch ----------------
extern "C" void kernel_launch(void* const* d_in, const int* in_sizes, int n_in,
                              void* d_out, int out_size, void* d_ws, size_t ws_size,
                              hipStream_t stream) {
    const float* query  = (const float*)d_in[0];
    const float* relpos = (const float*)d_in[1];
    const float* w_in   = (const float*)d_in[2];
    const float* b_in   = (const float*)d_in[3];
    const float* w_out  = (const float*)d_in[4];
    const float* b_out  = (const float*)d_in[5];
    float* out = (float*)d_out;

    char* ws = (char*)d_ws;
    size_t off = 0;
    auto alloc = [&](size_t bytes) {
        void* p = ws + off;
        off += (bytes + 255) & ~(size_t)255;
        return p;
    };
    __bf16* qA    = (__bf16*)alloc((size_t)M1 * EE * 2);        // query bf16
    __bf16* winb  = (__bf16*)alloc((size_t)3 * EE * EE * 2);    // in_proj_weight bf16
    __bf16* woutb = (__bf16*)alloc((size_t)EE * EE * 2);        // out_proj_weight bf16
    __bf16* erfp  = (__bf16*)alloc((size_t)SL * DD * 2);        // flipped er bf16
    __bf16* q_ws  = (__bf16*)alloc((size_t)BHC * SL * DD * 2);
    __bf16* k_ws  = (__bf16*)alloc((size_t)BHC * SL * DD * 2);
    __bf16* v_ws  = (__bf16*)alloc((size_t)BHC * SL * DD * 2);
    __bf16* vT_ws = (__bf16*)alloc((size_t)BHC * SL * DD * 2);
    __bf16* O_flat= (__bf16*)alloc((size_t)M1 * EE * 2);

    f32_to_bf16_k<<<4096, 256, 0, stream>>>(query, qA, M1 * EE);
    f32_to_bf16_k<<<3072, 256, 0, stream>>>(w_in, winb, 3 * EE * EE);
    f32_to_bf16_k<<<1024, 256, 0, stream>>>(w_out, woutb, EE * EE);
    erflip_k<<<256, 256, 0, stream>>>(relpos, erfp);

    // qkv projection: M=4096, N=3072, K=1024
    gemm_bt<<<(3072 / BNt) * (M1 / BMt), 256, 0, stream>>>(
        qA, winb, b_in, M1, 3072, EE, 0, q_ws, k_ws, v_ws, nullptr);

    transpose_v<<<BHC * 16, 256, 0, stream>>>(v_ws, vT_ws);

    attn_kernel<<<BHC * 16, 256, 0, stream>>>(q_ws, k_ws, vT_ws, erfp, O_flat);

    // out projection: M=4096, N=1024, K=1024
    gemm_bt<<<(1024 / BNt) * (M1 / BMt), 256, 0, stream>>>(
        O_flat, woutb, b_out, M1, 1024, EE, 1, nullptr, nullptr, nullptr, out);
}